// Round 8
// baseline (5141.959 us; speedup 1.0000x reference)
//
#include <hip/hip_runtime.h>
#include <math.h>

// Model dims (fixed by the reference)
#define Lc   6
#define Dc   1024
#define FFc  4096
#define Vc   32000
#define Bc   2
#define Sc   1024
#define Hc   16
#define GSc  128
#define DHc  64
#define Mc   (Bc * Sc)   // 2048 token rows

typedef __attribute__((ext_vector_type(8))) short bf16x8;   // 8 bf16 (4 VGPRs)
typedef __attribute__((ext_vector_type(4))) float f32x4;    // 4 fp32 acc

// pack two f32 into two bf16 (truncation — exact for ternary; hi of split)
__device__ inline unsigned ph2(float a, float b) {
    return (__float_as_uint(b) & 0xffff0000u) | (__float_as_uint(a) >> 16);
}
// low residual of the bf16 split: a - trunc_bf16(a)
__device__ inline float flo(float a) {
    return a - __uint_as_float(__float_as_uint(a) & 0xffff0000u);
}
__device__ inline ushort bhi(float a) { return (ushort)(__float_as_uint(a) >> 16); }
__device__ inline ushort blo(float a) { return (ushort)(__float_as_uint(flo(a)) >> 16); }
__device__ inline float unbf(ushort h) { return __uint_as_float((unsigned)h << 16); }

// Byte offset into a SWIZZLED bf16 buffer of logical [rows][K] elems:
// within each row's 128-B chunk, 16-B groups are XOR-permuted by (row&7).
// Makes global_load_lds (linear LDS dest) reproduce the GEMM's conflict-free
// LDS layout exactly (pre-swizzled-source pattern).
__device__ inline size_t swz_bidx(int row, int col, int K) {
    size_t byte = (size_t)col * 2;
    size_t base = (size_t)row * K * 2 + (byte & ~(size_t)127);
    int inner = (int)(byte & 127);
    inner = (inner & 15) | ((((inner >> 4) ^ (row & 7)) & 7) << 4);
    return base + (size_t)inner;
}

// async global->LDS DMA, 16 B per lane (dest = wave-uniform base + lane*16)
__device__ inline void glds16(const void* g, void* l) {
    __builtin_amdgcn_global_load_lds(
        (const __attribute__((address_space(1))) void*)g,
        (__attribute__((address_space(3))) void*)l, 16, 0, 0);
}

// NOTE (round-7 post-mortem): no XCD block swizzle.  The NATURAL grid
// (x = M-block fastest, gridDim.x = 16) gives XCD = bid%8 = m%8, so each
// XCD permanently owns 2 M-stripes of A (L2-resident) while weight panels
// are shared via the die-level L3.  The round-7 swizzle broke this and
// tripled HBM traffic (FETCH 585MB -> 1.57GB, WRITE 256MB -> 1.87GB).

// ---------------------------------------------------------------------------
// Block-wide reduction (256 threads = 4 waves of 64)
// ---------------------------------------------------------------------------
__device__ inline float block_reduce_sum(float v, float* scratch) {
    __syncthreads();
    int lane = threadIdx.x & 63, w = threadIdx.x >> 6;
#pragma unroll
    for (int off = 32; off > 0; off >>= 1) v += __shfl_down(v, off, 64);
    if (lane == 0) scratch[w] = v;
    __syncthreads();
    if (threadIdx.x == 0) scratch[0] = scratch[0] + scratch[1] + scratch[2] + scratch[3];
    __syncthreads();
    return scratch[0];
}

// ---------------------------------------------------------------------------
// Embedding gather + dequant + pos add.  grid = Mc blocks, 256 thr.
// ---------------------------------------------------------------------------
__global__ __launch_bounds__(256) void k_embed(const int* __restrict__ ids,
                                               const float* __restrict__ et,
                                               const float* __restrict__ es,
                                               const float* __restrict__ pos,
                                               float* __restrict__ x) {
    int row = blockIdx.x;
    int sp  = row & (Sc - 1);
    int d   = threadIdx.x << 2;
    int idx = ids[row];
    int base = idx * Dc + d;
    float4 t = *(const float4*)(et + base);
    float  s = es[base >> 7];
    float4 p = *(const float4*)(pos + sp * Dc + d);
    float4 o;
    o.x = fmaf(t.x, s, p.x); o.y = fmaf(t.y, s, p.y);
    o.z = fmaf(t.z, s, p.z); o.w = fmaf(t.w, s, p.w);
    *(float4*)(x + row * Dc + d) = o;
}

// ---------------------------------------------------------------------------
// RMSNorm -> SWIZZLED bf16 hi/lo split output (hi+lo == f32 exactly).
// ---------------------------------------------------------------------------
__global__ __launch_bounds__(256) void k_rmsnorm_bf(const float* __restrict__ x,
                                                    const float* __restrict__ w,
                                                    ushort* __restrict__ hi,
                                                    ushort* __restrict__ lo) {
    __shared__ float scratch[4];
    int row = blockIdx.x;
    int d = threadIdx.x << 2;
    float4 f = *(const float4*)(x + (size_t)row * Dc + d);
    float s = f.x * f.x + f.y * f.y + f.z * f.z + f.w * f.w;
    s = block_reduce_sum(s, scratch);
    float rinv = rsqrtf(s * (1.0f / Dc) + 1e-6f);
    float4 wv = *(const float4*)(w + d);
    float o0 = f.x * rinv * wv.x, o1 = f.y * rinv * wv.y;
    float o2 = f.z * rinv * wv.z, o3 = f.w * rinv * wv.w;
    ushort4 hv, lv;
    hv.x = bhi(o0); hv.y = bhi(o1); hv.z = bhi(o2); hv.w = bhi(o3);
    lv.x = blo(o0); lv.y = blo(o1); lv.z = blo(o2); lv.w = blo(o3);
    const size_t sb = swz_bidx(row, d, Dc);
    *(ushort4*)((char*)hi + sb) = hv;
    *(ushort4*)((char*)lo + sb) = lv;
}

// ---------------------------------------------------------------------------
// MFMA fused-dequant GEMM core (ROUND-4 VERIFIED STRUCTURE, 3 blocks/CU).
//  - 128x128 tile, BK=64, 256 thr = 4 waves 2x2, 49,664 B LDS.
//  - A (pre-split, pre-swizzled bf16 hi/lo) staged via global_load_lds DMA.
//  - B (ternary f32) prefetched to regs one sub-tile ahead (HBM latency
//    hides under the MFMA phase).
//  - fp32 group scales applied per 128-K via accg drain.
//  - [g0,g1) group range enables split-K.
// ---------------------------------------------------------------------------
template <bool RESID>
__device__ __forceinline__ void gemm_core(
    const ushort* __restrict__ Ahi, const ushort* __restrict__ Alo,
    const float* __restrict__ Wt, const float* __restrict__ Ws,
    const float* __restrict__ R, float* __restrict__ C,
    const int bn, const int N, const int K, const int g0, const int g1) {
    __shared__ char Ah[16384];
    __shared__ char Al[16384];
    __shared__ char Bh[16384];
    __shared__ float Wsl[128];

    const int tid  = threadIdx.x;
    const int lane = tid & 63;
    const int wv   = tid >> 6;
    const int wm   = (wv >> 1) << 6;
    const int wn   = (wv & 1) << 6;
    const int bm   = blockIdx.x << 7;
    const int kg   = K >> 7;

    // B staging coords: thread -> (row 0..127, 64B half)
    const int sr   = tid >> 1;
    const int sh   = tid & 1;
    const int swr  = (sr & 7) << 4;
    const int rowb = sr << 7;
    const int colb = sh << 6;
    const float* Bbase = Wt + (size_t)(bn + sr) * K + (sh << 5);

    // A DMA coords: round i in {0..3}: rows (i<<5)+gr, 16-B chunk gc
    const int gr = (wv << 3) + (lane >> 3);
    const int gc = (lane & 7) << 4;
    const char* Abh = (const char*)Ahi;
    const char* Abl = (const char*)Alo;

    // fragment read coords
    const int lr  = lane & 15;
    const int lkb = (lane >> 4) << 4;
    const int frs = (lane & 7) << 4;

    f32x4 acc[4][4], accg[4][4];
#pragma unroll
    for (int i = 0; i < 4; ++i)
#pragma unroll
        for (int j = 0; j < 4; ++j) {
            acc[i][j]  = (f32x4){0.f, 0.f, 0.f, 0.f};
            accg[i][j] = (f32x4){0.f, 0.f, 0.f, 0.f};
        }

    float4 bv[8];
    const int s0 = g0 << 1, s1 = g1 << 1;
    {   // prologue: prefetch B for first sub-tile
        const float4* p = (const float4*)(Bbase + (s0 << 6));
#pragma unroll
        for (int jj = 0; jj < 8; ++jj) bv[jj] = p[jj];
    }

    for (int s = s0; s < s1; ++s) {
        const int k0 = s << 6;
        __syncthreads();   // prev MFMA reads done -> LDS writable
        // issue A hi/lo DMA (lands by next barrier's vmcnt drain)
#pragma unroll
        for (int i = 0; i < 4; ++i) {
            const size_t sb = ((size_t)(bm + gr + (i << 5)) * K + k0) * 2 + gc;
            glds16(Abh + sb, Ah + (wv << 10) + (i << 12));
            glds16(Abl + sb, Al + (wv << 10) + (i << 12));
        }
        if ((s & 1) == 0 && tid < 128)
            Wsl[tid] = Ws[(size_t)(bn + tid) * kg + (s >> 1)];
        // convert & write B (prefetched last iteration)
#pragma unroll
        for (int j = 0; j < 4; ++j) {
            const int ob = rowb + ((colb + (j << 4)) ^ swr);
            float4 x0 = bv[2 * j], x1 = bv[2 * j + 1];
            *(uint4*)(Bh + ob) = make_uint4(ph2(x0.x, x0.y), ph2(x0.z, x0.w),
                                            ph2(x1.x, x1.y), ph2(x1.z, x1.w));
        }
        __syncthreads();   // drains A DMA; Bh visible
        if (s + 1 < s1) {  // prefetch next B under the MFMA phase
            const float4* p = (const float4*)(Bbase + ((s + 1) << 6));
#pragma unroll
            for (int jj = 0; jj < 8; ++jj) bv[jj] = p[jj];
        }
#pragma unroll
        for (int ks = 0; ks < 2; ++ks) {
            bf16x8 fa[4], fl[4], fb[4];
            const int cb = ((ks << 6) + lkb) ^ frs;
#pragma unroll
            for (int f = 0; f < 4; ++f) {
                const int ra = (wm + (f << 4) + lr) << 7;
                fa[f] = *(const bf16x8*)(Ah + ra + cb);
                fl[f] = *(const bf16x8*)(Al + ra + cb);
                const int rb = (wn + (f << 4) + lr) << 7;
                fb[f] = *(const bf16x8*)(Bh + rb + cb);
            }
#pragma unroll
            for (int i = 0; i < 4; ++i)
#pragma unroll
                for (int j = 0; j < 4; ++j) {
                    accg[i][j] = __builtin_amdgcn_mfma_f32_16x16x32_bf16(fa[i], fb[j], accg[i][j], 0, 0, 0);
                    accg[i][j] = __builtin_amdgcn_mfma_f32_16x16x32_bf16(fl[i], fb[j], accg[i][j], 0, 0, 0);
                }
        }
        if (s & 1) {  // drain group accumulator with fp32 scales
            float sv[4];
#pragma unroll
            for (int j = 0; j < 4; ++j) sv[j] = Wsl[wn + (j << 4) + lr];
#pragma unroll
            for (int i = 0; i < 4; ++i)
#pragma unroll
                for (int j = 0; j < 4; ++j) {
                    acc[i][j] += accg[i][j] * sv[j];
                    accg[i][j] = (f32x4){0.f, 0.f, 0.f, 0.f};
                }
        }
    }

    // epilogue: C/D layout col = lane&15, row = (lane>>4)*4 + reg
    const int r0 = (blockIdx.x << 7) + wm + ((lane >> 4) << 2);
    const int c0 = bn + wn + lr;
#pragma unroll
    for (int i = 0; i < 4; ++i) {
        const int row = r0 + (i << 4);
#pragma unroll
        for (int j = 0; j < 4; ++j) {
            size_t off = (size_t)row * N + c0 + (j << 4);
#pragma unroll
            for (int e = 0; e < 4; ++e) {
                float vv = acc[i][j][e];
                if (RESID) vv += R[off];
                C[off] = vv;
                off += (size_t)N;
            }
        }
    }
}

// Head GEMM (natural grid (16, N/128))
__global__ __launch_bounds__(256, 3) void k_gemm_head(
    const ushort* __restrict__ Ahi, const ushort* __restrict__ Alo,
    const float* __restrict__ Wt, const float* __restrict__ Ws,
    float* __restrict__ C, int N, int K) {
    gemm_core<false>(Ahi, Alo, Wt, Ws, nullptr, C, blockIdx.y << 7, N, K, 0, K >> 7);
}

// Split-K partial GEMM: grid (16, N/128, 4); slice z covers gper groups.
__global__ __launch_bounds__(256, 3) void k_gemm_part(
    const ushort* __restrict__ Ahi, const ushort* __restrict__ Alo,
    const float* __restrict__ Wt, const float* __restrict__ Ws,
    float* __restrict__ P, int N, int K, int gper) {
    const int z = blockIdx.z;
    gemm_core<false>(Ahi, Alo, Wt, Ws, nullptr, P + (size_t)z * Mc * Dc,
                     blockIdx.y << 7, N, K, z * gper, (z + 1) * gper);
}

// Fused q/k/v projection: grid (16, 24); y -> (proj, panel of 8)
__global__ __launch_bounds__(256, 3) void k_gemm_qkv(
    const ushort* __restrict__ Ahi, const ushort* __restrict__ Alo,
    const float* __restrict__ qt, const float* __restrict__ qs,
    const float* __restrict__ kt, const float* __restrict__ ks,
    const float* __restrict__ vt, const float* __restrict__ vs,
    float* __restrict__ qb, float* __restrict__ kb, float* __restrict__ vb) {
    const int which = blockIdx.y >> 3;
    const int bn = (blockIdx.y & 7) << 7;
    const float* Wt = which == 0 ? qt : which == 1 ? kt : vt;
    const float* Ws = which == 0 ? qs : which == 1 ? ks : vs;
    float* C = which == 0 ? qb : which == 1 ? kb : vb;
    gemm_core<false>(Ahi, Alo, Wt, Ws, nullptr, C, bn, Dc, Dc, 0, Dc >> 7);
}

// Fused gate/up projection: grid (16, 64); y -> (which, panel of 32)
__global__ __launch_bounds__(256, 3) void k_gemm_gu(
    const ushort* __restrict__ Ahi, const ushort* __restrict__ Alo,
    const float* __restrict__ gt, const float* __restrict__ gs,
    const float* __restrict__ ut, const float* __restrict__ us,
    float* __restrict__ gate, float* __restrict__ up) {
    const int which = blockIdx.y >> 5;
    const int bn = (blockIdx.y & 31) << 7;
    const float* Wt = which == 0 ? gt : ut;
    const float* Ws = which == 0 ? gs : us;
    float* C = which == 0 ? gate : up;
    gemm_core<false>(Ahi, Alo, Wt, Ws, nullptr, C, bn, FFc, Dc, 0, Dc >> 7);
}

// ---------------------------------------------------------------------------
// Split-K reduce: x += p0+p1+p2+p3 (fp32, in-place residual add)
// ---------------------------------------------------------------------------
__global__ __launch_bounds__(256) void k_red4(const float* __restrict__ p,
                                              float* __restrict__ x) {
    const size_t i = (((size_t)blockIdx.x << 8) + threadIdx.x) << 2;
    const size_t st = (size_t)Mc * Dc;
    float4 a  = *(const float4*)(x + i);
    float4 p0 = *(const float4*)(p + i);
    float4 p1 = *(const float4*)(p + i + st);
    float4 p2 = *(const float4*)(p + i + 2 * st);
    float4 p3 = *(const float4*)(p + i + 3 * st);
    a.x += p0.x + p1.x + p2.x + p3.x;
    a.y += p0.y + p1.y + p2.y + p3.y;
    a.z += p0.z + p1.z + p2.z + p3.z;
    a.w += p0.w + p1.w + p2.w + p3.w;
    *(float4*)(x + i) = a;
}

// ---------------------------------------------------------------------------
// Elementwise  ff = silu(g) * u  -> SWIZZLED bf16 hi/lo (feeds down-proj A)
// ---------------------------------------------------------------------------
__global__ __launch_bounds__(256) void k_silumul(const float* __restrict__ g,
                                                 const float* __restrict__ u,
                                                 ushort* __restrict__ fhi,
                                                 ushort* __restrict__ fl2) {
    const size_t i = (((size_t)blockIdx.x << 8) + threadIdx.x) << 2;
    float4 gv = *(const float4*)(g + i);
    float4 uv = *(const float4*)(u + i);
    float r0 = uv.x * (gv.x / (1.0f + expf(-gv.x)));
    float r1 = uv.y * (gv.y / (1.0f + expf(-gv.y)));
    float r2 = uv.z * (gv.z / (1.0f + expf(-gv.z)));
    float r3 = uv.w * (gv.w / (1.0f + expf(-gv.w)));
    ushort4 hv, lv;
    hv.x = bhi(r0); hv.y = bhi(r1); hv.z = bhi(r2); hv.w = bhi(r3);
    lv.x = blo(r0); lv.y = blo(r1); lv.z = blo(r2); lv.w = blo(r3);
    const int row = (int)(i >> 12);            // FFc = 4096
    const int col = (int)(i & 4095);
    const size_t sb = swz_bidx(row, col, FFc);
    *(ushort4*)((char*)fhi + sb) = hv;
    *(ushort4*)((char*)fl2 + sb) = lv;
}

// ---------------------------------------------------------------------------
// Flash-style MFMA attention with CAUSAL LOAD BALANCE.
// grid = (S/128, H, B) = (8, 16, 2); each block processes q-tile pair
// {bx, 15-bx} -> constant 17 KV-tiles per block (was 1..16, wall = 31).
// Inner body identical to the round-4-verified kernel.
// ---------------------------------------------------------------------------
__global__ __launch_bounds__(256, 2) void k_attn_mfma(
    const float* __restrict__ q, const float* __restrict__ k,
    const float* __restrict__ v, const ushort* __restrict__ hnhi,
    const ushort* __restrict__ hnlo, const float* __restrict__ alpha,
    ushort* __restrict__ aohi, ushort* __restrict__ aolo) {
    __shared__ uint4 KhV[512], KlV[512];     // K [key][dh] hi/lo
    __shared__ uint4 VthV[512], VtlV[512];   // V^T [dh][key] hi/lo
    __shared__ uint4 PhV[512], PlV[512];     // P per-wave [16 q][64 key] hi/lo
    char* Khc  = (char*)KhV;
    char* Klc  = (char*)KlV;
    char* Vthc = (char*)VthV;
    char* Vtlc = (char*)VtlV;

    const int hh = blockIdx.y, b = blockIdx.z;
    const int tid  = threadIdx.x;
    const int lane = tid & 63, w = tid >> 6;
    const int lr = lane & 15, g = lane >> 4;
    const int bS = b * Sc;
    const int hoff = hh * DHc;
    const float al = alpha[hh];

    char* myPh = (char*)PhV + (w << 11);
    char* myPl = (char*)PlV + (w << 11);

    const int skey = tid >> 2, sseg = tid & 3;
    const int k4 = (tid >> 4) << 2, d4 = (tid & 15) << 2;

#pragma unroll 1
    for (int half = 0; half < 2; ++half) {
        const int t = half ? ((Sc / 64) - 1 - (int)blockIdx.x) : (int)blockIdx.x;

        const int qrow = (t << 6) + (w << 4) + lr;
        bf16x8 qh[2], ql[2];
        {
            const float* qp = q + (size_t)(bS + qrow) * Dc + hoff + (g << 3);
#pragma unroll
            for (int c = 0; c < 2; ++c) {
                float4 f0 = *(const float4*)(qp + (c << 5));
                float4 f1 = *(const float4*)(qp + (c << 5) + 4);
                float s[8] = {f0.x * 0.125f, f0.y * 0.125f, f0.z * 0.125f, f0.w * 0.125f,
                              f1.x * 0.125f, f1.y * 0.125f, f1.z * 0.125f, f1.w * 0.125f};
                union { bf16x8 v; unsigned u[4]; } Hh, Ll;
#pragma unroll
                for (int p = 0; p < 4; ++p) {
                    Hh.u[p] = ph2(s[2 * p], s[2 * p + 1]);
                    Ll.u[p] = ph2(flo(s[2 * p]), flo(s[2 * p + 1]));
                }
                qh[c] = Hh.v; ql[c] = Ll.v;
            }
        }

        f32x4 oacc[4];
        float m[4], lsum[4];
#pragma unroll
        for (int f = 0; f < 4; ++f) oacc[f] = (f32x4){0.f, 0.f, 0.f, 0.f};
#pragma unroll
        for (int e = 0; e < 4; ++e) { m[e] = -3.0e38f; lsum[e] = 0.f; }

        float4 kr[4], vr[4];
        {
            const float* src = k + (size_t)(bS + skey) * Dc + hoff + (sseg << 4);
#pragma unroll
            for (int r = 0; r < 4; ++r) kr[r] = *(const float4*)(src + (r << 2));
            const float* vsrc = v + (size_t)(bS + k4) * Dc + hoff + d4;
#pragma unroll
            for (int r = 0; r < 4; ++r) vr[r] = *(const float4*)(vsrc + r * Dc);
        }

        const int nt = t + 1;
        for (int j = 0; j < nt; ++j) {
            {
                const int swz = (skey & 7) << 4;
                char* dsth = Khc + skey * 128;
                char* dstl = Klc + skey * 128;
                float4 a0 = kr[0], a1 = kr[1], a2 = kr[2], a3 = kr[3];
                *(uint4*)(dsth + (((sseg << 5)) ^ swz)) =
                    make_uint4(ph2(a0.x, a0.y), ph2(a0.z, a0.w), ph2(a1.x, a1.y), ph2(a1.z, a1.w));
                *(uint4*)(dsth + (((sseg << 5) + 16) ^ swz)) =
                    make_uint4(ph2(a2.x, a2.y), ph2(a2.z, a2.w), ph2(a3.x, a3.y), ph2(a3.z, a3.w));
                *(uint4*)(dstl + (((sseg << 5)) ^ swz)) =
                    make_uint4(ph2(flo(a0.x), flo(a0.y)), ph2(flo(a0.z), flo(a0.w)),
                               ph2(flo(a1.x), flo(a1.y)), ph2(flo(a1.z), flo(a1.w)));
                *(uint4*)(dstl + (((sseg << 5) + 16) ^ swz)) =
                    make_uint4(ph2(flo(a2.x), flo(a2.y)), ph2(flo(a2.z), flo(a2.w)),
                               ph2(flo(a3.x), flo(a3.y)), ph2(flo(a3.z), flo(a3.w)));
            }
            {
                union { float4 v4; float f[4]; } r0, r1, r2, r3;
                r0.v4 = vr[0]; r1.v4 = vr[1]; r2.v4 = vr[2]; r3.v4 = vr[3];
#pragma unroll
                for (int d = 0; d < 4; ++d) {
                    const int dh = d4 + d;
                    const int byt = dh * 128 + (((k4 << 1)) ^ ((dh & 7) << 4));
                    float x0 = r0.f[d], x1 = r1.f[d], x2 = r2.f[d], x3 = r3.f[d];
                    *(uint2*)(Vthc + byt) = make_uint2(ph2(x0, x1), ph2(x2, x3));
                    *(uint2*)(Vtlc + byt) =
                        make_uint2(ph2(flo(x0), flo(x1)), ph2(flo(x2), flo(x3)));
                }
            }
            __syncthreads();
            if (j + 1 < nt) {
                const int kb2 = (j + 1) << 6;
                const float* src = k + (size_t)(bS + kb2 + skey) * Dc + hoff + (sseg << 4);
#pragma unroll
                for (int r = 0; r < 4; ++r) kr[r] = *(const float4*)(src + (r << 2));
                const float* vsrc = v + (size_t)(bS + kb2 + k4) * Dc + hoff + d4;
#pragma unroll
                for (int r = 0; r < 4; ++r) vr[r] = *(const float4*)(vsrc + r * Dc);
            }

            f32x4 sacc[4];
#pragma unroll
            for (int f = 0; f < 4; ++f) sacc[f] = (f32x4){0.f, 0.f, 0.f, 0.f};
#pragma unroll
            for (int c = 0; c < 2; ++c) {
                const int cb = (c << 6) + (g << 4);
#pragma unroll
                for (int f = 0; f < 4; ++f) {
                    const int row = (f << 4) + lr;
                    const int byt = row * 128 + (cb ^ ((row & 7) << 4));
                    bf16x8 kh = *(const bf16x8*)(Khc + byt);
                    bf16x8 kl = *(const bf16x8*)(Klc + byt);
                    sacc[f] = __builtin_amdgcn_mfma_f32_16x16x32_bf16(qh[c], kh, sacc[f], 0, 0, 0);
                    sacc[f] = __builtin_amdgcn_mfma_f32_16x16x32_bf16(ql[c], kh, sacc[f], 0, 0, 0);
                    sacc[f] = __builtin_amdgcn_mfma_f32_16x16x32_bf16(qh[c], kl, sacc[f], 0, 0, 0);
                }
            }
            if (j == t) {
                const int qloc = (w << 4) + (g << 2);
#pragma unroll
                for (int f = 0; f < 4; ++f) {
                    const int key = (f << 4) + lr;
#pragma unroll
                    for (int e = 0; e < 4; ++e)
                        if (key > qloc + e) sacc[f][e] = -3.0e38f;
                }
            }
            float rmax[4], corr[4], rsum[4];
#pragma unroll
            for (int e = 0; e < 4; ++e)
                rmax[e] = fmaxf(fmaxf(sacc[0][e], sacc[1][e]), fmaxf(sacc[2][e], sacc[3][e]));
#pragma unroll
            for (int msk = 1; msk <= 8; msk <<= 1)
#pragma unroll
                for (int e = 0; e < 4; ++e)
                    rmax[e] = fmaxf(rmax[e], __shfl_xor(rmax[e], msk, 64));
#pragma unroll
            for (int e = 0; e < 4; ++e) {
                float mn = fmaxf(m[e], rmax[e]);
                corr[e] = __expf(m[e] - mn);
                m[e] = mn;
                rsum[e] = 0.f;
            }
#pragma unroll
            for (int f = 0; f < 4; ++f)
#pragma unroll
                for (int e = 0; e < 4; ++e) {
                    float p = __expf(sacc[f][e] - m[e]);
                    sacc[f][e] = p;
                    rsum[e] += p;
                }
#pragma unroll
            for (int msk = 1; msk <= 8; msk <<= 1)
#pragma unroll
                for (int e = 0; e < 4; ++e) rsum[e] += __shfl_xor(rsum[e], msk, 64);
#pragma unroll
            for (int e = 0; e < 4; ++e) lsum[e] = lsum[e] * corr[e] + rsum[e];
#pragma unroll
            for (int f = 0; f < 4; ++f)
#pragma unroll
                for (int e = 0; e < 4; ++e) oacc[f][e] *= corr[e];

#pragma unroll
            for (int f = 0; f < 4; ++f) {
                const int key2 = ((f << 4) + lr) << 1;
#pragma unroll
                for (int e = 0; e < 4; ++e) {
                    const int qr = (g << 2) + e;
                    const int byt = qr * 128 + (key2 ^ ((qr & 7) << 4));
                    unsigned bits = __float_as_uint(sacc[f][e]);
                    unsigned hib = bits & 0xffff0000u;
                    *(short*)(myPh + byt) = (short)(hib >> 16);
                    float lov = sacc[f][e] - __uint_as_float(hib);
                    *(short*)(myPl + byt) = (short)(__float_as_uint(lov) >> 16);
                }
            }
#pragma unroll
            for (int c = 0; c < 2; ++c) {
                const int cb = (c << 6) + (g << 4);
                const int pbyt = lr * 128 + (cb ^ ((lr & 7) << 4));
                bf16x8 pah = *(const bf16x8*)(myPh + pbyt);
                bf16x8 pal = *(const bf16x8*)(myPl + pbyt);
#pragma unroll
                for (int f = 0; f < 4; ++f) {
                    const int row = (f << 4) + lr;
                    const int byt = row * 128 + (cb ^ ((row & 7) << 4));
                    bf16x8 vbh = *(const bf16x8*)(Vthc + byt);
                    bf16x8 vbl = *(const bf16x8*)(Vtlc + byt);
                    oacc[f] = __builtin_amdgcn_mfma_f32_16x16x32_bf16(pah, vbh, oacc[f], 0, 0, 0);
                    oacc[f] = __builtin_amdgcn_mfma_f32_16x16x32_bf16(pal, vbh, oacc[f], 0, 0, 0);
                    oacc[f] = __builtin_amdgcn_mfma_f32_16x16x32_bf16(pah, vbl, oacc[f], 0, 0, 0);
                }
            }
            __syncthreads();
        }

        float invl[4];
#pragma unroll
        for (int e = 0; e < 4; ++e) invl[e] = 1.0f / lsum[e];
#pragma unroll
        for (int f = 0; f < 4; ++f) {
            const int dh = (f << 4) + lr;
#pragma unroll
            for (int e = 0; e < 4; ++e) {
                const int qg = (t << 6) + (w << 4) + (g << 2) + e;
                const int row = bS + qg;
                const size_t sb = swz_bidx(row, hoff + dh, Dc);
                float hnv = unbf(*(const ushort*)((const char*)hnhi + sb)) +
                            unbf(*(const ushort*)((const char*)hnlo + sb));
                float val = fmaf(al, hnv, oacc[f][e] * invl[e]);
                *(ushort*)((char*)aohi + sb) = bhi(val);
                *(ushort*)((char*)aolo + sb) = blo(val);
            }
        }
        __syncthreads();   // epilogue done before next half re-stages LDS
    }
}

// ---------------------------------------------------------------------------
// Launcher
// ---------------------------------------------------------------------------
extern "C" void kernel_launch(void* const* d_in, const int* in_sizes, int n_in,
                              void* d_out, int out_size, void* d_ws, size_t ws_size,
                              hipStream_t stream) {
    const int*   ids    = (const int*)d_in[0];
    const float* emb_t  = (const float*)d_in[1];
    const float* emb_s  = (const float*)d_in[2];
    const float* pos    = (const float*)d_in[3];
    const float* q_t    = (const float*)d_in[4];
    const float* q_s    = (const float*)d_in[5];
    const float* k_t    = (const float*)d_in[6];
    const float* k_s    = (const float*)d_in[7];
    const float* v_t    = (const float*)d_in[8];
    const float* v_s    = (const float*)d_in[9];
    const float* o_t    = (const float*)d_in[10];
    const float* o_s    = (const float*)d_in[11];
    const float* g_t    = (const float*)d_in[12];
    const float* g_s    = (const float*)d_in[13];
    const float* u_t    = (const float*)d_in[14];
    const float* u_s    = (const float*)d_in[15];
    const float* dd_t   = (const float*)d_in[16];
    const float* dd_s   = (const float*)d_in[17];
    const float* alpha  = (const float*)d_in[18];
    const float* na_w   = (const float*)d_in[19];
    const float* nm_w   = (const float*)d_in[20];
    const float* nf_w   = (const float*)d_in[21];
    const float* head_t = (const float*)d_in[22];
    const float* head_s = (const float*)d_in[23];
    float* outp = (float*)d_out;

    // ws layout:
    //   x    : Mc*Dc f32
    //   hbf  : hhi/hlo bf16 (swizzled)
    //   big  : Mc*FFc f32 — attn: qb|kb|vb f32 + ao bf16 hi/lo;
    //          MLP: up f32, then down-proj split-K partials (4 x Mc*Dc).
    // d_out scratch until head GEMM:
    //   [0, 33.5MB)  : gate f32  /  o-proj split-K partials (32 MB)
    //   [33.5, 67MB) : ff bf16 hi/lo (down-proj A)
    float*  ws   = (float*)d_ws;
    float*  x    = ws;
    ushort* hhi  = (ushort*)(x + (size_t)Mc * Dc);
    ushort* hlo  = hhi + (size_t)Mc * Dc;
    float*  big  = (float*)(hlo + (size_t)Mc * Dc);
    float*  qb   = big;
    float*  kb   = big + (size_t)Mc * Dc;
    float*  vb   = big + (size_t)2 * Mc * Dc;
    ushort* aohi = (ushort*)(big + (size_t)3 * Mc * Dc);
    ushort* aolo = aohi + (size_t)Mc * Dc;
    float*  up   = big;               // MLP phase reuse
    float*  gate = (float*)d_out;     // scratch until head GEMM
    float*  partO = (float*)d_out;    // o-proj partials share the gate slot
    ushort* ffhi = (ushort*)((char*)d_out + (size_t)Mc * FFc * 4);
    ushort* fflo = ffhi + (size_t)Mc * FFc;

    k_embed<<<Mc, 256, 0, stream>>>(ids, emb_t, emb_s, pos, x);

    const dim3 gQKV(Mc / 128, 24);         // 384 blocks
    const dim3 gGU(Mc / 128, 64);          // 1024 blocks
    const dim3 gSK(Mc / 128, 8, 4);        // 512 blocks (o-proj / down-proj)
    const dim3 gH(Mc / 128, Vc / 128);     // (16, 250)
    const dim3 gA(Sc / 128, Hc, Bc);       // (8, 16, 2) balanced pairs
    const int  gSilu = (Mc * FFc) / (256 * 4);
    const int  gRed  = (Mc * Dc) / (256 * 4);

    for (int l = 0; l < Lc; ++l) {
        const float* qt = q_t + (size_t)l * Dc * Dc;
        const float* qs = q_s + (size_t)l * (Dc * Dc / GSc);
        const float* kt = k_t + (size_t)l * Dc * Dc;
        const float* ks = k_s + (size_t)l * (Dc * Dc / GSc);
        const float* vt = v_t + (size_t)l * Dc * Dc;
        const float* vs = v_s + (size_t)l * (Dc * Dc / GSc);
        const float* ot = o_t + (size_t)l * Dc * Dc;
        const float* os = o_s + (size_t)l * (Dc * Dc / GSc);
        const float* gt = g_t + (size_t)l * FFc * Dc;
        const float* gs = g_s + (size_t)l * (FFc * Dc / GSc);
        const float* ut = u_t + (size_t)l * FFc * Dc;
        const float* us = u_s + (size_t)l * (FFc * Dc / GSc);
        const float* dt = dd_t + (size_t)l * Dc * FFc;
        const float* ds = dd_s + (size_t)l * (Dc * FFc / GSc);

        k_rmsnorm_bf<<<Mc, 256, 0, stream>>>(x, na_w + l * Dc, hhi, hlo);
        k_gemm_qkv<<<gQKV, 256, 0, stream>>>(hhi, hlo, qt, qs, kt, ks, vt, vs, qb, kb, vb);
        k_attn_mfma<<<gA, 256, 0, stream>>>(qb, kb, vb, hhi, hlo, alpha + l * Hc, aohi, aolo);
        k_gemm_part<<<gSK, 256, 0, stream>>>(aohi, aolo, ot, os, partO, Dc, Dc, 2);
        k_red4<<<gRed, 256, 0, stream>>>(partO, x);
        k_rmsnorm_bf<<<Mc, 256, 0, stream>>>(x, nm_w + l * Dc, hhi, hlo);
        k_gemm_gu<<<gGU, 256, 0, stream>>>(hhi, hlo, gt, gs, ut, us, gate, up);
        k_silumul<<<gSilu, 256, 0, stream>>>(gate, up, ffhi, fflo);
        k_gemm_part<<<gSK, 256, 0, stream>>>(ffhi, fflo, dt, ds, big, Dc, FFc, 8);
        k_red4<<<gRed, 256, 0, stream>>>(big, x);
    }

    k_rmsnorm_bf<<<Mc, 256, 0, stream>>>(x, nf_w, hhi, hlo);
    k_gemm_head<<<gH, 256, 0, stream>>>(hhi, hlo, head_t, head_s, outp, Vc, Dc);
}

// Round 9
// 3033.344 us; speedup vs baseline: 1.6951x; 1.6951x over previous
//
#include <hip/hip_runtime.h>
#include <math.h>

// Model dims (fixed by the reference)
#define Lc   6
#define Dc   1024
#define FFc  4096
#define Vc   32000
#define Bc   2
#define Sc   1024
#define Hc   16
#define GSc  128
#define DHc  64
#define Mc   (Bc * Sc)   // 2048 token rows

typedef __attribute__((ext_vector_type(8))) short bf16x8;   // 8 bf16 (4 VGPRs)
typedef __attribute__((ext_vector_type(4))) float f32x4;    // 4 fp32 acc

// pack two f32 into two bf16 (truncation — exact for ternary; hi of split)
__device__ inline unsigned ph2(float a, float b) {
    return (__float_as_uint(b) & 0xffff0000u) | (__float_as_uint(a) >> 16);
}
// low residual of the bf16 split: a - trunc_bf16(a)
__device__ inline float flo(float a) {
    return a - __uint_as_float(__float_as_uint(a) & 0xffff0000u);
}
__device__ inline ushort bhi(float a) { return (ushort)(__float_as_uint(a) >> 16); }
__device__ inline ushort blo(float a) { return (ushort)(__float_as_uint(flo(a)) >> 16); }
__device__ inline float unbf(ushort h) { return __uint_as_float((unsigned)h << 16); }

// Byte offset into a SWIZZLED bf16 buffer of logical [rows][K] elems:
// within each row's 128-B chunk, 16-B groups are XOR-permuted by (row&7).
__device__ inline size_t swz_bidx(int row, int col, int K) {
    size_t byte = (size_t)col * 2;
    size_t base = (size_t)row * K * 2 + (byte & ~(size_t)127);
    int inner = (int)(byte & 127);
    inner = (inner & 15) | ((((inner >> 4) ^ (row & 7)) & 7) << 4);
    return base + (size_t)inner;
}

// async global->LDS DMA, 16 B per lane (dest = wave-uniform base + lane*16)
__device__ inline void glds16(const void* g, void* l) {
    __builtin_amdgcn_global_load_lds(
        (const __attribute__((address_space(1))) void*)g,
        (__attribute__((address_space(3))) void*)l, 16, 0, 0);
}

// POST-MORTEMS baked in:
//  - r7: no XCD block swizzle (natural grid keeps A stripes L2-resident).
//  - r8: __launch_bounds__(256,2) on ALL GEMMs.  (256,3) capped the
//    register budget below the 128-VGPR accumulator state -> scratch
//    spill -> +1.3GB FETCH / +1.6GB WRITE per head dispatch (VGPR_Count
//    84 vs 120 was the smoking gun).  2 blocks/CU is the no-spill point.

// ---------------------------------------------------------------------------
// Block-wide reduction (256 threads = 4 waves of 64)
// ---------------------------------------------------------------------------
__device__ inline float block_reduce_sum(float v, float* scratch) {
    __syncthreads();
    int lane = threadIdx.x & 63, w = threadIdx.x >> 6;
#pragma unroll
    for (int off = 32; off > 0; off >>= 1) v += __shfl_down(v, off, 64);
    if (lane == 0) scratch[w] = v;
    __syncthreads();
    if (threadIdx.x == 0) scratch[0] = scratch[0] + scratch[1] + scratch[2] + scratch[3];
    __syncthreads();
    return scratch[0];
}

// ---------------------------------------------------------------------------
// Embedding gather + dequant + pos add.  grid = Mc blocks, 256 thr.
// ---------------------------------------------------------------------------
__global__ __launch_bounds__(256) void k_embed(const int* __restrict__ ids,
                                               const float* __restrict__ et,
                                               const float* __restrict__ es,
                                               const float* __restrict__ pos,
                                               float* __restrict__ x) {
    int row = blockIdx.x;
    int sp  = row & (Sc - 1);
    int d   = threadIdx.x << 2;
    int idx = ids[row];
    int base = idx * Dc + d;
    float4 t = *(const float4*)(et + base);
    float  s = es[base >> 7];
    float4 p = *(const float4*)(pos + sp * Dc + d);
    float4 o;
    o.x = fmaf(t.x, s, p.x); o.y = fmaf(t.y, s, p.y);
    o.z = fmaf(t.z, s, p.z); o.w = fmaf(t.w, s, p.w);
    *(float4*)(x + row * Dc + d) = o;
}

// ---------------------------------------------------------------------------
// RMSNorm -> SWIZZLED bf16 hi/lo split output (hi+lo == f32 exactly).
// ---------------------------------------------------------------------------
__global__ __launch_bounds__(256) void k_rmsnorm_bf(const float* __restrict__ x,
                                                    const float* __restrict__ w,
                                                    ushort* __restrict__ hi,
                                                    ushort* __restrict__ lo) {
    __shared__ float scratch[4];
    int row = blockIdx.x;
    int d = threadIdx.x << 2;
    float4 f = *(const float4*)(x + (size_t)row * Dc + d);
    float s = f.x * f.x + f.y * f.y + f.z * f.z + f.w * f.w;
    s = block_reduce_sum(s, scratch);
    float rinv = rsqrtf(s * (1.0f / Dc) + 1e-6f);
    float4 wv = *(const float4*)(w + d);
    float o0 = f.x * rinv * wv.x, o1 = f.y * rinv * wv.y;
    float o2 = f.z * rinv * wv.z, o3 = f.w * rinv * wv.w;
    ushort4 hv, lv;
    hv.x = bhi(o0); hv.y = bhi(o1); hv.z = bhi(o2); hv.w = bhi(o3);
    lv.x = blo(o0); lv.y = blo(o1); lv.z = blo(o2); lv.w = blo(o3);
    const size_t sb = swz_bidx(row, d, Dc);
    *(ushort4*)((char*)hi + sb) = hv;
    *(ushort4*)((char*)lo + sb) = lv;
}

// ---------------------------------------------------------------------------
// MFMA fused-dequant GEMM core (ROUND-4 VERIFIED: 2 blocks/CU, no spill).
//  - 128x128 tile, BK=64, 256 thr = 4 waves 2x2, 49,664 B LDS.
//  - A (pre-split, pre-swizzled bf16 hi/lo) staged via global_load_lds DMA.
//  - B (ternary f32) prefetched to regs one sub-tile ahead.
//  - fp32 group scales applied per 128-K via accg drain.
//  - [g0,g1) group range enables split-K.
// ---------------------------------------------------------------------------
template <bool RESID>
__device__ __forceinline__ void gemm_core(
    const ushort* __restrict__ Ahi, const ushort* __restrict__ Alo,
    const float* __restrict__ Wt, const float* __restrict__ Ws,
    const float* __restrict__ R, float* __restrict__ C,
    const int bn, const int N, const int K, const int g0, const int g1) {
    __shared__ char Ah[16384];
    __shared__ char Al[16384];
    __shared__ char Bh[16384];
    __shared__ float Wsl[128];

    const int tid  = threadIdx.x;
    const int lane = tid & 63;
    const int wv   = tid >> 6;
    const int wm   = (wv >> 1) << 6;
    const int wn   = (wv & 1) << 6;
    const int bm   = blockIdx.x << 7;
    const int kg   = K >> 7;

    // B staging coords: thread -> (row 0..127, 64B half)
    const int sr   = tid >> 1;
    const int sh   = tid & 1;
    const int swr  = (sr & 7) << 4;
    const int rowb = sr << 7;
    const int colb = sh << 6;
    const float* Bbase = Wt + (size_t)(bn + sr) * K + (sh << 5);

    // A DMA coords: round i in {0..3}: rows (i<<5)+gr, 16-B chunk gc
    const int gr = (wv << 3) + (lane >> 3);
    const int gc = (lane & 7) << 4;
    const char* Abh = (const char*)Ahi;
    const char* Abl = (const char*)Alo;

    // fragment read coords
    const int lr  = lane & 15;
    const int lkb = (lane >> 4) << 4;
    const int frs = (lane & 7) << 4;

    f32x4 acc[4][4], accg[4][4];
#pragma unroll
    for (int i = 0; i < 4; ++i)
#pragma unroll
        for (int j = 0; j < 4; ++j) {
            acc[i][j]  = (f32x4){0.f, 0.f, 0.f, 0.f};
            accg[i][j] = (f32x4){0.f, 0.f, 0.f, 0.f};
        }

    float4 bv[8];
    const int s0 = g0 << 1, s1 = g1 << 1;
    {   // prologue: prefetch B for first sub-tile
        const float4* p = (const float4*)(Bbase + (s0 << 6));
#pragma unroll
        for (int jj = 0; jj < 8; ++jj) bv[jj] = p[jj];
    }

    for (int s = s0; s < s1; ++s) {
        const int k0 = s << 6;
        __syncthreads();   // prev MFMA reads done -> LDS writable
        // issue A hi/lo DMA (lands by next barrier's vmcnt drain)
#pragma unroll
        for (int i = 0; i < 4; ++i) {
            const size_t sb = ((size_t)(bm + gr + (i << 5)) * K + k0) * 2 + gc;
            glds16(Abh + sb, Ah + (wv << 10) + (i << 12));
            glds16(Abl + sb, Al + (wv << 10) + (i << 12));
        }
        if ((s & 1) == 0 && tid < 128)
            Wsl[tid] = Ws[(size_t)(bn + tid) * kg + (s >> 1)];
        // convert & write B (prefetched last iteration)
#pragma unroll
        for (int j = 0; j < 4; ++j) {
            const int ob = rowb + ((colb + (j << 4)) ^ swr);
            float4 x0 = bv[2 * j], x1 = bv[2 * j + 1];
            *(uint4*)(Bh + ob) = make_uint4(ph2(x0.x, x0.y), ph2(x0.z, x0.w),
                                            ph2(x1.x, x1.y), ph2(x1.z, x1.w));
        }
        __syncthreads();   // drains A DMA; Bh visible
        if (s + 1 < s1) {  // prefetch next B under the MFMA phase
            const float4* p = (const float4*)(Bbase + ((s + 1) << 6));
#pragma unroll
            for (int jj = 0; jj < 8; ++jj) bv[jj] = p[jj];
        }
#pragma unroll
        for (int ks = 0; ks < 2; ++ks) {
            bf16x8 fa[4], fl[4], fb[4];
            const int cb = ((ks << 6) + lkb) ^ frs;
#pragma unroll
            for (int f = 0; f < 4; ++f) {
                const int ra = (wm + (f << 4) + lr) << 7;
                fa[f] = *(const bf16x8*)(Ah + ra + cb);
                fl[f] = *(const bf16x8*)(Al + ra + cb);
                const int rb = (wn + (f << 4) + lr) << 7;
                fb[f] = *(const bf16x8*)(Bh + rb + cb);
            }
#pragma unroll
            for (int i = 0; i < 4; ++i)
#pragma unroll
                for (int j = 0; j < 4; ++j) {
                    accg[i][j] = __builtin_amdgcn_mfma_f32_16x16x32_bf16(fa[i], fb[j], accg[i][j], 0, 0, 0);
                    accg[i][j] = __builtin_amdgcn_mfma_f32_16x16x32_bf16(fl[i], fb[j], accg[i][j], 0, 0, 0);
                }
        }
        if (s & 1) {  // drain group accumulator with fp32 scales
            float sv[4];
#pragma unroll
            for (int j = 0; j < 4; ++j) sv[j] = Wsl[wn + (j << 4) + lr];
#pragma unroll
            for (int i = 0; i < 4; ++i)
#pragma unroll
                for (int j = 0; j < 4; ++j) {
                    acc[i][j] += accg[i][j] * sv[j];
                    accg[i][j] = (f32x4){0.f, 0.f, 0.f, 0.f};
                }
        }
    }

    // epilogue: C/D layout col = lane&15, row = (lane>>4)*4 + reg
    const int r0 = bm + wm + ((lane >> 4) << 2);
    const int c0 = bn + wn + lr;
#pragma unroll
    for (int i = 0; i < 4; ++i) {
        const int row = r0 + (i << 4);
#pragma unroll
        for (int j = 0; j < 4; ++j) {
            size_t off = (size_t)row * N + c0 + (j << 4);
#pragma unroll
            for (int e = 0; e < 4; ++e) {
                float vv = acc[i][j][e];
                if (RESID) vv += R[off];
                C[off] = vv;
                off += (size_t)N;
            }
        }
    }
}

// Head GEMM (natural grid (16, N/128))
__global__ __launch_bounds__(256, 2) void k_gemm_head(
    const ushort* __restrict__ Ahi, const ushort* __restrict__ Alo,
    const float* __restrict__ Wt, const float* __restrict__ Ws,
    float* __restrict__ C, int N, int K) {
    gemm_core<false>(Ahi, Alo, Wt, Ws, nullptr, C, blockIdx.y << 7, N, K, 0, K >> 7);
}

// Split-K partial GEMM: grid (16, N/128, 4); slice z covers gper groups.
__global__ __launch_bounds__(256, 2) void k_gemm_part(
    const ushort* __restrict__ Ahi, const ushort* __restrict__ Alo,
    const float* __restrict__ Wt, const float* __restrict__ Ws,
    float* __restrict__ P, int N, int K, int gper) {
    const int z = blockIdx.z;
    gemm_core<false>(Ahi, Alo, Wt, Ws, nullptr, P + (size_t)z * Mc * Dc,
                     blockIdx.y << 7, N, K, z * gper, (z + 1) * gper);
}

// Fused q/k/v projection: grid (16, 24); y -> (proj, panel of 8)
__global__ __launch_bounds__(256, 2) void k_gemm_qkv(
    const ushort* __restrict__ Ahi, const ushort* __restrict__ Alo,
    const float* __restrict__ qt, const float* __restrict__ qs,
    const float* __restrict__ kt, const float* __restrict__ ks,
    const float* __restrict__ vt, const float* __restrict__ vs,
    float* __restrict__ qb, float* __restrict__ kb, float* __restrict__ vb) {
    const int which = blockIdx.y >> 3;
    const int bn = (blockIdx.y & 7) << 7;
    const float* Wt = which == 0 ? qt : which == 1 ? kt : vt;
    const float* Ws = which == 0 ? qs : which == 1 ? ks : vs;
    float* C = which == 0 ? qb : which == 1 ? kb : vb;
    gemm_core<false>(Ahi, Alo, Wt, Ws, nullptr, C, bn, Dc, Dc, 0, Dc >> 7);
}

// Fused gate/up projection: grid (16, 64); y -> (which, panel of 32)
__global__ __launch_bounds__(256, 2) void k_gemm_gu(
    const ushort* __restrict__ Ahi, const ushort* __restrict__ Alo,
    const float* __restrict__ gt, const float* __restrict__ gs,
    const float* __restrict__ ut, const float* __restrict__ us,
    float* __restrict__ gate, float* __restrict__ up) {
    const int which = blockIdx.y >> 5;
    const int bn = (blockIdx.y & 31) << 7;
    const float* Wt = which == 0 ? gt : ut;
    const float* Ws = which == 0 ? gs : us;
    float* C = which == 0 ? gate : up;
    gemm_core<false>(Ahi, Alo, Wt, Ws, nullptr, C, bn, FFc, Dc, 0, Dc >> 7);
}

// ---------------------------------------------------------------------------
// Split-K reduce: x += p0+p1+p2+p3 (fp32, in-place residual add)
// ---------------------------------------------------------------------------
__global__ __launch_bounds__(256) void k_red4(const float* __restrict__ p,
                                              float* __restrict__ x) {
    const size_t i = (((size_t)blockIdx.x << 8) + threadIdx.x) << 2;
    const size_t st = (size_t)Mc * Dc;
    float4 a  = *(const float4*)(x + i);
    float4 p0 = *(const float4*)(p + i);
    float4 p1 = *(const float4*)(p + i + st);
    float4 p2 = *(const float4*)(p + i + 2 * st);
    float4 p3 = *(const float4*)(p + i + 3 * st);
    a.x += p0.x + p1.x + p2.x + p3.x;
    a.y += p0.y + p1.y + p2.y + p3.y;
    a.z += p0.z + p1.z + p2.z + p3.z;
    a.w += p0.w + p1.w + p2.w + p3.w;
    *(float4*)(x + i) = a;
}

// ---------------------------------------------------------------------------
// Elementwise  ff = silu(g) * u  -> SWIZZLED bf16 hi/lo (feeds down-proj A)
// ---------------------------------------------------------------------------
__global__ __launch_bounds__(256) void k_silumul(const float* __restrict__ g,
                                                 const float* __restrict__ u,
                                                 ushort* __restrict__ fhi,
                                                 ushort* __restrict__ fl2) {
    const size_t i = (((size_t)blockIdx.x << 8) + threadIdx.x) << 2;
    float4 gv = *(const float4*)(g + i);
    float4 uv = *(const float4*)(u + i);
    float r0 = uv.x * (gv.x / (1.0f + expf(-gv.x)));
    float r1 = uv.y * (gv.y / (1.0f + expf(-gv.y)));
    float r2 = uv.z * (gv.z / (1.0f + expf(-gv.z)));
    float r3 = uv.w * (gv.w / (1.0f + expf(-gv.w)));
    ushort4 hv, lv;
    hv.x = bhi(r0); hv.y = bhi(r1); hv.z = bhi(r2); hv.w = bhi(r3);
    lv.x = blo(r0); lv.y = blo(r1); lv.z = blo(r2); lv.w = blo(r3);
    const int row = (int)(i >> 12);            // FFc = 4096
    const int col = (int)(i & 4095);
    const size_t sb = swz_bidx(row, col, FFc);
    *(ushort4*)((char*)fhi + sb) = hv;
    *(ushort4*)((char*)fl2 + sb) = lv;
}

// ---------------------------------------------------------------------------
// Flash-style MFMA attention with CAUSAL LOAD BALANCE (verified round 8).
// grid = (S/128, H, B) = (8, 16, 2); each block processes q-tile pair
// {bx, 15-bx} -> constant 17 KV-tiles per block.
// ---------------------------------------------------------------------------
__global__ __launch_bounds__(256, 2) void k_attn_mfma(
    const float* __restrict__ q, const float* __restrict__ k,
    const float* __restrict__ v, const ushort* __restrict__ hnhi,
    const ushort* __restrict__ hnlo, const float* __restrict__ alpha,
    ushort* __restrict__ aohi, ushort* __restrict__ aolo) {
    __shared__ uint4 KhV[512], KlV[512];     // K [key][dh] hi/lo
    __shared__ uint4 VthV[512], VtlV[512];   // V^T [dh][key] hi/lo
    __shared__ uint4 PhV[512], PlV[512];     // P per-wave [16 q][64 key] hi/lo
    char* Khc  = (char*)KhV;
    char* Klc  = (char*)KlV;
    char* Vthc = (char*)VthV;
    char* Vtlc = (char*)VtlV;

    const int hh = blockIdx.y, b = blockIdx.z;
    const int tid  = threadIdx.x;
    const int lane = tid & 63, w = tid >> 6;
    const int lr = lane & 15, g = lane >> 4;
    const int bS = b * Sc;
    const int hoff = hh * DHc;
    const float al = alpha[hh];

    char* myPh = (char*)PhV + (w << 11);
    char* myPl = (char*)PlV + (w << 11);

    const int skey = tid >> 2, sseg = tid & 3;
    const int k4 = (tid >> 4) << 2, d4 = (tid & 15) << 2;

#pragma unroll 1
    for (int half = 0; half < 2; ++half) {
        const int t = half ? ((Sc / 64) - 1 - (int)blockIdx.x) : (int)blockIdx.x;

        const int qrow = (t << 6) + (w << 4) + lr;
        bf16x8 qh[2], ql[2];
        {
            const float* qp = q + (size_t)(bS + qrow) * Dc + hoff + (g << 3);
#pragma unroll
            for (int c = 0; c < 2; ++c) {
                float4 f0 = *(const float4*)(qp + (c << 5));
                float4 f1 = *(const float4*)(qp + (c << 5) + 4);
                float s[8] = {f0.x * 0.125f, f0.y * 0.125f, f0.z * 0.125f, f0.w * 0.125f,
                              f1.x * 0.125f, f1.y * 0.125f, f1.z * 0.125f, f1.w * 0.125f};
                union { bf16x8 v; unsigned u[4]; } Hh, Ll;
#pragma unroll
                for (int p = 0; p < 4; ++p) {
                    Hh.u[p] = ph2(s[2 * p], s[2 * p + 1]);
                    Ll.u[p] = ph2(flo(s[2 * p]), flo(s[2 * p + 1]));
                }
                qh[c] = Hh.v; ql[c] = Ll.v;
            }
        }

        f32x4 oacc[4];
        float m[4], lsum[4];
#pragma unroll
        for (int f = 0; f < 4; ++f) oacc[f] = (f32x4){0.f, 0.f, 0.f, 0.f};
#pragma unroll
        for (int e = 0; e < 4; ++e) { m[e] = -3.0e38f; lsum[e] = 0.f; }

        float4 kr[4], vr[4];
        {
            const float* src = k + (size_t)(bS + skey) * Dc + hoff + (sseg << 4);
#pragma unroll
            for (int r = 0; r < 4; ++r) kr[r] = *(const float4*)(src + (r << 2));
            const float* vsrc = v + (size_t)(bS + k4) * Dc + hoff + d4;
#pragma unroll
            for (int r = 0; r < 4; ++r) vr[r] = *(const float4*)(vsrc + r * Dc);
        }

        const int nt = t + 1;
        for (int j = 0; j < nt; ++j) {
            {
                const int swz = (skey & 7) << 4;
                char* dsth = Khc + skey * 128;
                char* dstl = Klc + skey * 128;
                float4 a0 = kr[0], a1 = kr[1], a2 = kr[2], a3 = kr[3];
                *(uint4*)(dsth + (((sseg << 5)) ^ swz)) =
                    make_uint4(ph2(a0.x, a0.y), ph2(a0.z, a0.w), ph2(a1.x, a1.y), ph2(a1.z, a1.w));
                *(uint4*)(dsth + (((sseg << 5) + 16) ^ swz)) =
                    make_uint4(ph2(a2.x, a2.y), ph2(a2.z, a2.w), ph2(a3.x, a3.y), ph2(a3.z, a3.w));
                *(uint4*)(dstl + (((sseg << 5)) ^ swz)) =
                    make_uint4(ph2(flo(a0.x), flo(a0.y)), ph2(flo(a0.z), flo(a0.w)),
                               ph2(flo(a1.x), flo(a1.y)), ph2(flo(a1.z), flo(a1.w)));
                *(uint4*)(dstl + (((sseg << 5) + 16) ^ swz)) =
                    make_uint4(ph2(flo(a2.x), flo(a2.y)), ph2(flo(a2.z), flo(a2.w)),
                               ph2(flo(a3.x), flo(a3.y)), ph2(flo(a3.z), flo(a3.w)));
            }
            {
                union { float4 v4; float f[4]; } r0, r1, r2, r3;
                r0.v4 = vr[0]; r1.v4 = vr[1]; r2.v4 = vr[2]; r3.v4 = vr[3];
#pragma unroll
                for (int d = 0; d < 4; ++d) {
                    const int dh = d4 + d;
                    const int byt = dh * 128 + (((k4 << 1)) ^ ((dh & 7) << 4));
                    float x0 = r0.f[d], x1 = r1.f[d], x2 = r2.f[d], x3 = r3.f[d];
                    *(uint2*)(Vthc + byt) = make_uint2(ph2(x0, x1), ph2(x2, x3));
                    *(uint2*)(Vtlc + byt) =
                        make_uint2(ph2(flo(x0), flo(x1)), ph2(flo(x2), flo(x3)));
                }
            }
            __syncthreads();
            if (j + 1 < nt) {
                const int kb2 = (j + 1) << 6;
                const float* src = k + (size_t)(bS + kb2 + skey) * Dc + hoff + (sseg << 4);
#pragma unroll
                for (int r = 0; r < 4; ++r) kr[r] = *(const float4*)(src + (r << 2));
                const float* vsrc = v + (size_t)(bS + kb2 + k4) * Dc + hoff + d4;
#pragma unroll
                for (int r = 0; r < 4; ++r) vr[r] = *(const float4*)(vsrc + r * Dc);
            }

            f32x4 sacc[4];
#pragma unroll
            for (int f = 0; f < 4; ++f) sacc[f] = (f32x4){0.f, 0.f, 0.f, 0.f};
#pragma unroll
            for (int c = 0; c < 2; ++c) {
                const int cb = (c << 6) + (g << 4);
#pragma unroll
                for (int f = 0; f < 4; ++f) {
                    const int row = (f << 4) + lr;
                    const int byt = row * 128 + (cb ^ ((row & 7) << 4));
                    bf16x8 kh = *(const bf16x8*)(Khc + byt);
                    bf16x8 kl = *(const bf16x8*)(Klc + byt);
                    sacc[f] = __builtin_amdgcn_mfma_f32_16x16x32_bf16(qh[c], kh, sacc[f], 0, 0, 0);
                    sacc[f] = __builtin_amdgcn_mfma_f32_16x16x32_bf16(ql[c], kh, sacc[f], 0, 0, 0);
                    sacc[f] = __builtin_amdgcn_mfma_f32_16x16x32_bf16(qh[c], kl, sacc[f], 0, 0, 0);
                }
            }
            if (j == t) {
                const int qloc = (w << 4) + (g << 2);
#pragma unroll
                for (int f = 0; f < 4; ++f) {
                    const int key = (f << 4) + lr;
#pragma unroll
                    for (int e = 0; e < 4; ++e)
                        if (key > qloc + e) sacc[f][e] = -3.0e38f;
                }
            }
            float rmax[4], corr[4], rsum[4];
#pragma unroll
            for (int e = 0; e < 4; ++e)
                rmax[e] = fmaxf(fmaxf(sacc[0][e], sacc[1][e]), fmaxf(sacc[2][e], sacc[3][e]));
#pragma unroll
            for (int msk = 1; msk <= 8; msk <<= 1)
#pragma unroll
                for (int e = 0; e < 4; ++e)
                    rmax[e] = fmaxf(rmax[e], __shfl_xor(rmax[e], msk, 64));
#pragma unroll
            for (int e = 0; e < 4; ++e) {
                float mn = fmaxf(m[e], rmax[e]);
                corr[e] = __expf(m[e] - mn);
                m[e] = mn;
                rsum[e] = 0.f;
            }
#pragma unroll
            for (int f = 0; f < 4; ++f)
#pragma unroll
                for (int e = 0; e < 4; ++e) {
                    float p = __expf(sacc[f][e] - m[e]);
                    sacc[f][e] = p;
                    rsum[e] += p;
                }
#pragma unroll
            for (int msk = 1; msk <= 8; msk <<= 1)
#pragma unroll
                for (int e = 0; e < 4; ++e) rsum[e] += __shfl_xor(rsum[e], msk, 64);
#pragma unroll
            for (int e = 0; e < 4; ++e) lsum[e] = lsum[e] * corr[e] + rsum[e];
#pragma unroll
            for (int f = 0; f < 4; ++f)
#pragma unroll
                for (int e = 0; e < 4; ++e) oacc[f][e] *= corr[e];

#pragma unroll
            for (int f = 0; f < 4; ++f) {
                const int key2 = ((f << 4) + lr) << 1;
#pragma unroll
                for (int e = 0; e < 4; ++e) {
                    const int qr = (g << 2) + e;
                    const int byt = qr * 128 + (key2 ^ ((qr & 7) << 4));
                    unsigned bits = __float_as_uint(sacc[f][e]);
                    unsigned hib = bits & 0xffff0000u;
                    *(short*)(myPh + byt) = (short)(hib >> 16);
                    float lov = sacc[f][e] - __uint_as_float(hib);
                    *(short*)(myPl + byt) = (short)(__float_as_uint(lov) >> 16);
                }
            }
#pragma unroll
            for (int c = 0; c < 2; ++c) {
                const int cb = (c << 6) + (g << 4);
                const int pbyt = lr * 128 + (cb ^ ((lr & 7) << 4));
                bf16x8 pah = *(const bf16x8*)(myPh + pbyt);
                bf16x8 pal = *(const bf16x8*)(myPl + pbyt);
#pragma unroll
                for (int f = 0; f < 4; ++f) {
                    const int row = (f << 4) + lr;
                    const int byt = row * 128 + (cb ^ ((row & 7) << 4));
                    bf16x8 vbh = *(const bf16x8*)(Vthc + byt);
                    bf16x8 vbl = *(const bf16x8*)(Vtlc + byt);
                    oacc[f] = __builtin_amdgcn_mfma_f32_16x16x32_bf16(pah, vbh, oacc[f], 0, 0, 0);
                    oacc[f] = __builtin_amdgcn_mfma_f32_16x16x32_bf16(pal, vbh, oacc[f], 0, 0, 0);
                    oacc[f] = __builtin_amdgcn_mfma_f32_16x16x32_bf16(pah, vbl, oacc[f], 0, 0, 0);
                }
            }
            __syncthreads();
        }

        float invl[4];
#pragma unroll
        for (int e = 0; e < 4; ++e) invl[e] = 1.0f / lsum[e];
#pragma unroll
        for (int f = 0; f < 4; ++f) {
            const int dh = (f << 4) + lr;
#pragma unroll
            for (int e = 0; e < 4; ++e) {
                const int qg = (t << 6) + (w << 4) + (g << 2) + e;
                const int row = bS + qg;
                const size_t sb = swz_bidx(row, hoff + dh, Dc);
                float hnv = unbf(*(const ushort*)((const char*)hnhi + sb)) +
                            unbf(*(const ushort*)((const char*)hnlo + sb));
                float val = fmaf(al, hnv, oacc[f][e] * invl[e]);
                *(ushort*)((char*)aohi + sb) = bhi(val);
                *(ushort*)((char*)aolo + sb) = blo(val);
            }
        }
        __syncthreads();   // epilogue done before next half re-stages LDS
    }
}

// ---------------------------------------------------------------------------
// Launcher
// ---------------------------------------------------------------------------
extern "C" void kernel_launch(void* const* d_in, const int* in_sizes, int n_in,
                              void* d_out, int out_size, void* d_ws, size_t ws_size,
                              hipStream_t stream) {
    const int*   ids    = (const int*)d_in[0];
    const float* emb_t  = (const float*)d_in[1];
    const float* emb_s  = (const float*)d_in[2];
    const float* pos    = (const float*)d_in[3];
    const float* q_t    = (const float*)d_in[4];
    const float* q_s    = (const float*)d_in[5];
    const float* k_t    = (const float*)d_in[6];
    const float* k_s    = (const float*)d_in[7];
    const float* v_t    = (const float*)d_in[8];
    const float* v_s    = (const float*)d_in[9];
    const float* o_t    = (const float*)d_in[10];
    const float* o_s    = (const float*)d_in[11];
    const float* g_t    = (const float*)d_in[12];
    const float* g_s    = (const float*)d_in[13];
    const float* u_t    = (const float*)d_in[14];
    const float* u_s    = (const float*)d_in[15];
    const float* dd_t   = (const float*)d_in[16];
    const float* dd_s   = (const float*)d_in[17];
    const float* alpha  = (const float*)d_in[18];
    const float* na_w   = (const float*)d_in[19];
    const float* nm_w   = (const float*)d_in[20];
    const float* nf_w   = (const float*)d_in[21];
    const float* head_t = (const float*)d_in[22];
    const float* head_s = (const float*)d_in[23];
    float* outp = (float*)d_out;

    // ws layout:
    //   x    : Mc*Dc f32
    //   hbf  : hhi/hlo bf16 (swizzled)
    //   big  : Mc*FFc f32 — attn: qb|kb|vb f32 + ao bf16 hi/lo;
    //          MLP: up f32, then down-proj split-K partials (4 x Mc*Dc).
    // d_out scratch until head GEMM:
    //   [0, 33.5MB)  : gate f32  /  o-proj split-K partials (32 MB)
    //   [33.5, 67MB) : ff bf16 hi/lo (down-proj A)
    float*  ws   = (float*)d_ws;
    float*  x    = ws;
    ushort* hhi  = (ushort*)(x + (size_t)Mc * Dc);
    ushort* hlo  = hhi + (size_t)Mc * Dc;
    float*  big  = (float*)(hlo + (size_t)Mc * Dc);
    float*  qb   = big;
    float*  kb   = big + (size_t)Mc * Dc;
    float*  vb   = big + (size_t)2 * Mc * Dc;
    ushort* aohi = (ushort*)(big + (size_t)3 * Mc * Dc);
    ushort* aolo = aohi + (size_t)Mc * Dc;
    float*  up   = big;               // MLP phase reuse
    float*  gate = (float*)d_out;     // scratch until head GEMM
    float*  partO = (float*)d_out;    // o-proj partials share the gate slot
    ushort* ffhi = (ushort*)((char*)d_out + (size_t)Mc * FFc * 4);
    ushort* fflo = ffhi + (size_t)Mc * FFc;

    k_embed<<<Mc, 256, 0, stream>>>(ids, emb_t, emb_s, pos, x);

    const dim3 gQKV(Mc / 128, 24);         // 384 blocks
    const dim3 gGU(Mc / 128, 64);          // 1024 blocks
    const dim3 gSK(Mc / 128, 8, 4);        // 512 blocks (o-proj / down-proj)
    const dim3 gH(Mc / 128, Vc / 128);     // (16, 250)
    const dim3 gA(Sc / 128, Hc, Bc);       // (8, 16, 2) balanced pairs
    const int  gSilu = (Mc * FFc) / (256 * 4);
    const int  gRed  = (Mc * Dc) / (256 * 4);

    for (int l = 0; l < Lc; ++l) {
        const float* qt = q_t + (size_t)l * Dc * Dc;
        const float* qs = q_s + (size_t)l * (Dc * Dc / GSc);
        const float* kt = k_t + (size_t)l * Dc * Dc;
        const float* ks = k_s + (size_t)l * (Dc * Dc / GSc);
        const float* vt = v_t + (size_t)l * Dc * Dc;
        const float* vs = v_s + (size_t)l * (Dc * Dc / GSc);
        const float* ot = o_t + (size_t)l * Dc * Dc;
        const float* os = o_s + (size_t)l * (Dc * Dc / GSc);
        const float* gt = g_t + (size_t)l * FFc * Dc;
        const float* gs = g_s + (size_t)l * (FFc * Dc / GSc);
        const float* ut = u_t + (size_t)l * FFc * Dc;
        const float* us = u_s + (size_t)l * (FFc * Dc / GSc);
        const float* dt = dd_t + (size_t)l * Dc * FFc;
        const float* ds = dd_s + (size_t)l * (Dc * FFc / GSc);

        k_rmsnorm_bf<<<Mc, 256, 0, stream>>>(x, na_w + l * Dc, hhi, hlo);
        k_gemm_qkv<<<gQKV, 256, 0, stream>>>(hhi, hlo, qt, qs, kt, ks, vt, vs, qb, kb, vb);
        k_attn_mfma<<<gA, 256, 0, stream>>>(qb, kb, vb, hhi, hlo, alpha + l * Hc, aohi, aolo);
        k_gemm_part<<<gSK, 256, 0, stream>>>(aohi, aolo, ot, os, partO, Dc, Dc, 2);
        k_red4<<<gRed, 256, 0, stream>>>(partO, x);
        k_rmsnorm_bf<<<Mc, 256, 0, stream>>>(x, nm_w + l * Dc, hhi, hlo);
        k_gemm_gu<<<gGU, 256, 0, stream>>>(hhi, hlo, gt, gs, ut, us, gate, up);
        k_silumul<<<gSilu, 256, 0, stream>>>(gate, up, ffhi, fflo);
        k_gemm_part<<<gSK, 256, 0, stream>>>(ffhi, fflo, dt, ds, big, Dc, FFc, 8);
        k_red4<<<gRed, 256, 0, stream>>>(big, x);
    }

    k_rmsnorm_bf<<<Mc, 256, 0, stream>>>(x, nf_w, hhi, hlo);
    k_gemm_head<<<gH, 256, 0, stream>>>(hhi, hlo, head_t, head_s, outp, Vc, Dc);
}